// Round 10
// baseline (408.677 us; speedup 1.0000x reference)
//
#include <hip/hip_runtime.h>
#include <stdint.h>

typedef __bf16 bf16x8 __attribute__((ext_vector_type(8)));
typedef float  floatx4 __attribute__((ext_vector_type(4)));

__device__ __forceinline__ unsigned short f2b(float x){
    unsigned u = __float_as_uint(x);
    u = u + 0x7FFFu + ((u >> 16) & 1u);          // RNE
    return (unsigned short)(u >> 16);
}
__device__ __forceinline__ float b2f(unsigned short h){
    return __uint_as_float(((unsigned)h) << 16);
}

// ================= CSR build: reservation counting sort =======================
// bin = dst >> 7 (128 nodes/bin). Slab capacity 4096/bin (mean 2046, sigma~45).

__global__ __launch_bounds__(256) void k_scatter2(const int* __restrict__ src,
                                                  const int* __restrict__ dst,
                                                  int* __restrict__ gcur,
                                                  unsigned* __restrict__ slab,
                                                  int E_, int nbins){
    __shared__ int h[1024];
    int t = threadIdx.x, blk = blockIdx.x;
    for (int i = t; i < nbins; i += 256) h[i] = 0;
    __syncthreads();
    int base = blk * 8192;
    #pragma unroll
    for (int j = 0; j < 8; j++){
        int e = base + (j * 256 + t) * 4;
        if (e < E_){
            int4 d = *(const int4*)(dst + e);
            atomicAdd(&h[d.x >> 7], 1);
            atomicAdd(&h[d.y >> 7], 1);
            atomicAdd(&h[d.z >> 7], 1);
            atomicAdd(&h[d.w >> 7], 1);
        }
    }
    __syncthreads();
    for (int i = t; i < nbins; i += 256){
        int hv = h[i];
        h[i] = hv ? atomicAdd(&gcur[i], hv) : 0;
    }
    __syncthreads();
    #pragma unroll
    for (int j = 0; j < 8; j++){
        int e = base + (j * 256 + t) * 4;
        if (e < E_){
            int4 d = *(const int4*)(dst + e);
            int4 s = *(const int4*)(src + e);
            int p0 = atomicAdd(&h[d.x >> 7], 1);
            slab[(size_t)(d.x >> 7) * 4096 + p0] = ((unsigned)(d.x & 127) << 25) | (unsigned)s.x;
            int p1 = atomicAdd(&h[d.y >> 7], 1);
            slab[(size_t)(d.y >> 7) * 4096 + p1] = ((unsigned)(d.y & 127) << 25) | (unsigned)s.y;
            int p2 = atomicAdd(&h[d.z >> 7], 1);
            slab[(size_t)(d.z >> 7) * 4096 + p2] = ((unsigned)(d.z & 127) << 25) | (unsigned)s.z;
            int p3 = atomicAdd(&h[d.w >> 7], 1);
            slab[(size_t)(d.w >> 7) * 4096 + p3] = ((unsigned)(d.w & 127) << 25) | (unsigned)s.w;
        }
    }
}

__global__ __launch_bounds__(1024) void k_binscanB(const int* __restrict__ btot,
                                                   int* __restrict__ boff, int nbins){
    __shared__ int s[1024];
    int t = threadIdx.x;
    s[t] = (t < nbins) ? btot[t] : 0;
    __syncthreads();
    for (int o = 1; o < 1024; o <<= 1){
        int v = (t >= o) ? s[t - o] : 0;
        __syncthreads();
        s[t] += v;
        __syncthreads();
    }
    if (t == 0) boff[0] = 0;
    if (t < nbins) boff[t + 1] = s[t];
}

__global__ __launch_bounds__(256) void k_binsort(const unsigned* __restrict__ slab,
                                                 const int* __restrict__ boff,
                                                 int* __restrict__ csr,
                                                 int* __restrict__ cnt,
                                                 int* __restrict__ off,
                                                 float* __restrict__ dinv,
                                                 int n, int nbins){
    int b = blockIdx.x, t = threadIdx.x;
    int s0 = boff[b], len = boff[b + 1] - s0;
    if (len > 4096) len = 4096;
    const unsigned* seg = slab + (size_t)b * 4096;
    __shared__ int cl[128], sc[128], cur[128];
    __shared__ unsigned buf[4096], outb[4096];
    if (t < 128){ cl[t] = 0; cur[t] = 0; }
    __syncthreads();
    for (int i = t; i < len; i += 256) buf[i] = seg[i];
    __syncthreads();
    for (int i = t; i < len; i += 256) atomicAdd(&cl[buf[i] >> 25], 1);
    __syncthreads();
    if (t < 128) sc[t] = cl[t];
    __syncthreads();
    for (int o = 1; o < 128; o <<= 1){
        int v = 0;
        if (t < 128 && t >= o) v = sc[t - o];
        __syncthreads();
        if (t < 128) sc[t] += v;
        __syncthreads();
    }
    for (int i = t; i < len; i += 256){
        unsigned w = buf[i];
        int nd = (int)(w >> 25);
        int p = (sc[nd] - cl[nd]) + atomicAdd(&cur[nd], 1);
        outb[p] = w & 0x1FFFFFFu;
    }
    __syncthreads();
    for (int i = t; i < len; i += 256) csr[s0 + i] = (int)outb[i];
    if (t < 128){
        int node = b * 128 + t;
        if (node < n){
            cnt[node] = cl[t];
            off[node] = s0 + (sc[t] - cl[t]);
            dinv[node] = rsqrtf((float)cl[t] + 1.0f);
        }
    }
}

// -------- weight prep: W1 and W2 -> MFMA B-fragment order ---------------------
__global__ __launch_bounds__(256) void k_wconv(const float* __restrict__ W1,
                                               const float* __restrict__ W2,
                                               unsigned short* __restrict__ wf1,
                                               unsigned short* __restrict__ wf2){
    int f = blockIdx.x * 256 + threadIdx.x;
    if (f >= 3072) return;
    const float* W; unsigned short* o; int ncol, lf;
    if (f < 2048){ W = W1; o = wf1; ncol = 128; lf = f; }
    else         { W = W2; o = wf2; ncol = 64;  lf = f - 2048; }
    int lane = lf & 63;
    int ctkc = lf >> 6;
    int kc = ctkc & 3, ct = ctkc >> 2;
    int col = ct * 16 + (lane & 15);
    int k0  = kc * 32 + (lane >> 4) * 8;
    unsigned short* d = o + (size_t)lf * 8;
    #pragma unroll
    for (int j = 0; j < 8; j++) d[j] = f2b(W[(k0 + j) * ncol + col]);
}

// ---------------- GEMM1: hs1cb = bf16( (x @ W1) * dinv[row] ), column-blocked --
// hs1cb layout: [slice=col/16][node][col%16], 8 slices of 3.2 MB.
__global__ __launch_bounds__(256) void k_gemm1(const float* __restrict__ x,
                                               const unsigned short* __restrict__ wf,
                                               const float* __restrict__ dinv,
                                               unsigned short* __restrict__ hs, int n){
    __shared__ unsigned short Wl[16384];
    __shared__ unsigned short Al[64 * 136];
    int t = threadIdx.x;
    long rowBase = (long)blockIdx.x * 64;
    {
        const uint4* s4 = (const uint4*)wf;
        uint4* d4 = (uint4*)Wl;
        #pragma unroll
        for (int i = 0; i < 8; i++) d4[t + i * 256] = s4[t + i * 256];
    }
    {
        const float4* xs = (const float4*)(x + rowBase * 128);
        #pragma unroll
        for (int k = 0; k < 8; k++){
            int i = t + k * 256;
            int r = i >> 5, c4 = (i & 31) << 2;
            float4 v = make_float4(0.f, 0.f, 0.f, 0.f);
            if (rowBase + r < n) v = xs[i];
            unsigned lo = (unsigned)f2b(v.x) | ((unsigned)f2b(v.y) << 16);
            unsigned hi = (unsigned)f2b(v.z) | ((unsigned)f2b(v.w) << 16);
            *(uint2*)&Al[r * 136 + c4] = make_uint2(lo, hi);
        }
    }
    __syncthreads();
    int w = t >> 6, lane = t & 63, lr = lane & 15, q = lane >> 4;
    floatx4 zero = {0.f, 0.f, 0.f, 0.f};
    floatx4 acc[8];
    #pragma unroll
    for (int ct = 0; ct < 8; ct++) acc[ct] = zero;
    #pragma unroll
    for (int kc = 0; kc < 4; kc++){
        bf16x8 af = *(const bf16x8*)&Al[(w * 16 + lr) * 136 + kc * 32 + q * 8];
        #pragma unroll
        for (int ct = 0; ct < 8; ct++){
            bf16x8 bf = *(const bf16x8*)&Wl[((ct * 4 + kc) * 64 + lane) * 8];
            acc[ct] = __builtin_amdgcn_mfma_f32_16x16x32_bf16(af, bf, acc[ct], 0, 0, 0);
        }
    }
    long r0 = rowBase + w * 16 + q * 4;
    #pragma unroll
    for (int r = 0; r < 4; r++){
        long row = r0 + r;
        if (row >= n) continue;
        float dv = dinv[row];
        #pragma unroll
        for (int ct = 0; ct < 8; ct++)
            hs[((size_t)ct * n + row) * 16 + lr] = f2b(acc[ct][r] * dv);
    }
}

// ---- agg1, column-sliced: slice = blockIdx & 7 keeps the 3.2MB slice table
// resident in that XCD's L2. 8 nodes/wave (8 lanes x 4B = one 32B row-slice).
// z1cb[slice][node][16] = bf16(relu(dinv*(sum+self)+b1)), column-blocked.
__global__ __launch_bounds__(256) void k_cagg1(const unsigned short* __restrict__ hs,
                                               const int* __restrict__ off,
                                               const int* __restrict__ cnt,
                                               const int* __restrict__ csr,
                                               const float* __restrict__ dinv,
                                               const float* __restrict__ b1,
                                               unsigned short* __restrict__ z1,
                                               int n, int nblocks){
    int t = threadIdx.x;
    int slice = blockIdx.x & 7;
    int sblk = blockIdx.x >> 3;
    int nsb = nblocks >> 3;
    int wband = t >> 6, lane = t & 63;
    int g = lane >> 3, sub = lane & 7;
    const unsigned short* tab = hs + (size_t)slice * n * 16;
    unsigned short* zt = z1 + (size_t)slice * n * 16;
    float2 bb = *(const float2*)(b1 + slice * 16 + sub * 2);
    int node0 = (sblk * 4 + wband) * 8 + g;
    int stride = nsb * 4 * 8;
    for (int node = node0; node < n; node += stride){
        int start = off[node], c = cnt[node];
        float dv = dinv[node];
        unsigned v0 = *(const unsigned*)(tab + (size_t)node * 16 + sub * 2);
        float a0 = b2f((unsigned short)v0);
        float a1 = b2f((unsigned short)(v0 >> 16));
        int j = 0;
        for (; j + 8 <= c; j += 8){
            int i0 = __builtin_nontemporal_load(csr + start + j + 0);
            int i1 = __builtin_nontemporal_load(csr + start + j + 1);
            int i2 = __builtin_nontemporal_load(csr + start + j + 2);
            int i3 = __builtin_nontemporal_load(csr + start + j + 3);
            int i4 = __builtin_nontemporal_load(csr + start + j + 4);
            int i5 = __builtin_nontemporal_load(csr + start + j + 5);
            int i6 = __builtin_nontemporal_load(csr + start + j + 6);
            int i7 = __builtin_nontemporal_load(csr + start + j + 7);
            unsigned w0 = *(const unsigned*)(tab + (size_t)i0 * 16 + sub * 2);
            unsigned w1 = *(const unsigned*)(tab + (size_t)i1 * 16 + sub * 2);
            unsigned w2 = *(const unsigned*)(tab + (size_t)i2 * 16 + sub * 2);
            unsigned w3 = *(const unsigned*)(tab + (size_t)i3 * 16 + sub * 2);
            unsigned w4 = *(const unsigned*)(tab + (size_t)i4 * 16 + sub * 2);
            unsigned w5 = *(const unsigned*)(tab + (size_t)i5 * 16 + sub * 2);
            unsigned w6 = *(const unsigned*)(tab + (size_t)i6 * 16 + sub * 2);
            unsigned w7 = *(const unsigned*)(tab + (size_t)i7 * 16 + sub * 2);
            a0 += b2f((unsigned short)w0); a1 += b2f((unsigned short)(w0 >> 16));
            a0 += b2f((unsigned short)w1); a1 += b2f((unsigned short)(w1 >> 16));
            a0 += b2f((unsigned short)w2); a1 += b2f((unsigned short)(w2 >> 16));
            a0 += b2f((unsigned short)w3); a1 += b2f((unsigned short)(w3 >> 16));
            a0 += b2f((unsigned short)w4); a1 += b2f((unsigned short)(w4 >> 16));
            a0 += b2f((unsigned short)w5); a1 += b2f((unsigned short)(w5 >> 16));
            a0 += b2f((unsigned short)w6); a1 += b2f((unsigned short)(w6 >> 16));
            a0 += b2f((unsigned short)w7); a1 += b2f((unsigned short)(w7 >> 16));
        }
        for (; j < c; j++){
            int s = __builtin_nontemporal_load(csr + start + j);
            unsigned v = *(const unsigned*)(tab + (size_t)s * 16 + sub * 2);
            a0 += b2f((unsigned short)v);
            a1 += b2f((unsigned short)(v >> 16));
        }
        float z0 = fmaxf(fmaf(dv, a0, bb.x), 0.f);
        float zv = fmaxf(fmaf(dv, a1, bb.y), 0.f);
        *(unsigned*)(zt + (size_t)node * 16 + sub * 2) =
            (unsigned)f2b(z0) | ((unsigned)f2b(zv) << 16);
    }
}

// ---------------- GEMM2 (MFMA): hs2cb = bf16( (z1 @ W2) * dinv ), from z1cb ----
// A-tile staged from column-blocked z1; output column-blocked [4][node][16].
__global__ __launch_bounds__(256) void k_gemm2(const unsigned short* __restrict__ z1,
                                               const unsigned short* __restrict__ wf,
                                               const float* __restrict__ dinv,
                                               unsigned short* __restrict__ hs2, int n){
    __shared__ unsigned short Wl[8192];
    __shared__ unsigned short Al[64 * 136];
    int t = threadIdx.x;
    long rowBase = (long)blockIdx.x * 64;
    {
        const uint4* s4 = (const uint4*)wf;
        uint4* d4 = (uint4*)Wl;
        #pragma unroll
        for (int i = 0; i < 4; i++) d4[t + i * 256] = s4[t + i * 256];
    }
    {
        // z1cb: [s][node][16]; tile rows rowBase..rowBase+63, 8 slices, 2 halves
        #pragma unroll
        for (int k = 0; k < 4; k++){
            int i = t + k * 256;
            int s = i >> 7, r = (i >> 1) & 63, hh = i & 1;
            uint4 v = make_uint4(0u, 0u, 0u, 0u);
            long row = rowBase + r;
            if (row < n)
                v = *(const uint4*)(z1 + ((size_t)s * n + row) * 16 + hh * 8);
            *(uint4*)&Al[r * 136 + s * 16 + hh * 8] = v;
        }
    }
    __syncthreads();
    int w = t >> 6, lane = t & 63, lr = lane & 15, q = lane >> 4;
    floatx4 zero = {0.f, 0.f, 0.f, 0.f};
    floatx4 acc[4];
    #pragma unroll
    for (int ct = 0; ct < 4; ct++) acc[ct] = zero;
    #pragma unroll
    for (int kc = 0; kc < 4; kc++){
        bf16x8 af = *(const bf16x8*)&Al[(w * 16 + lr) * 136 + kc * 32 + q * 8];
        #pragma unroll
        for (int ct = 0; ct < 4; ct++){
            bf16x8 bf = *(const bf16x8*)&Wl[((ct * 4 + kc) * 64 + lane) * 8];
            acc[ct] = __builtin_amdgcn_mfma_f32_16x16x32_bf16(af, bf, acc[ct], 0, 0, 0);
        }
    }
    long r0 = rowBase + w * 16 + q * 4;
    #pragma unroll
    for (int r = 0; r < 4; r++){
        long row = r0 + r;
        if (row >= n) continue;
        float dv = dinv[row];
        #pragma unroll
        for (int ct = 0; ct < 4; ct++)
            hs2[((size_t)ct * n + row) * 16 + lr] = f2b(acc[ct][r] * dv);
    }
}

// ---- agg2, column-sliced: slice = blockIdx & 3 (3.2MB slice, L2-resident).
// z2[node][64] row-major fp-bf16 out for decode.
__global__ __launch_bounds__(256) void k_cagg2(const unsigned short* __restrict__ hs,
                                               const int* __restrict__ off,
                                               const int* __restrict__ cnt,
                                               const int* __restrict__ csr,
                                               const float* __restrict__ dinv,
                                               const float* __restrict__ b2,
                                               unsigned short* __restrict__ z2,
                                               int n, int nblocks){
    int t = threadIdx.x;
    int slice = blockIdx.x & 3;
    int sblk = blockIdx.x >> 2;
    int nsb = nblocks >> 2;
    int wband = t >> 6, lane = t & 63;
    int g = lane >> 3, sub = lane & 7;
    const unsigned short* tab = hs + (size_t)slice * n * 16;
    float2 bb = *(const float2*)(b2 + slice * 16 + sub * 2);
    int node0 = (sblk * 4 + wband) * 8 + g;
    int stride = nsb * 4 * 8;
    for (int node = node0; node < n; node += stride){
        int start = off[node], c = cnt[node];
        float dv = dinv[node];
        unsigned v0 = *(const unsigned*)(tab + (size_t)node * 16 + sub * 2);
        float a0 = b2f((unsigned short)v0);
        float a1 = b2f((unsigned short)(v0 >> 16));
        int j = 0;
        for (; j + 8 <= c; j += 8){
            int i0 = __builtin_nontemporal_load(csr + start + j + 0);
            int i1 = __builtin_nontemporal_load(csr + start + j + 1);
            int i2 = __builtin_nontemporal_load(csr + start + j + 2);
            int i3 = __builtin_nontemporal_load(csr + start + j + 3);
            int i4 = __builtin_nontemporal_load(csr + start + j + 4);
            int i5 = __builtin_nontemporal_load(csr + start + j + 5);
            int i6 = __builtin_nontemporal_load(csr + start + j + 6);
            int i7 = __builtin_nontemporal_load(csr + start + j + 7);
            unsigned w0 = *(const unsigned*)(tab + (size_t)i0 * 16 + sub * 2);
            unsigned w1 = *(const unsigned*)(tab + (size_t)i1 * 16 + sub * 2);
            unsigned w2 = *(const unsigned*)(tab + (size_t)i2 * 16 + sub * 2);
            unsigned w3 = *(const unsigned*)(tab + (size_t)i3 * 16 + sub * 2);
            unsigned w4 = *(const unsigned*)(tab + (size_t)i4 * 16 + sub * 2);
            unsigned w5 = *(const unsigned*)(tab + (size_t)i5 * 16 + sub * 2);
            unsigned w6 = *(const unsigned*)(tab + (size_t)i6 * 16 + sub * 2);
            unsigned w7 = *(const unsigned*)(tab + (size_t)i7 * 16 + sub * 2);
            a0 += b2f((unsigned short)w0); a1 += b2f((unsigned short)(w0 >> 16));
            a0 += b2f((unsigned short)w1); a1 += b2f((unsigned short)(w1 >> 16));
            a0 += b2f((unsigned short)w2); a1 += b2f((unsigned short)(w2 >> 16));
            a0 += b2f((unsigned short)w3); a1 += b2f((unsigned short)(w3 >> 16));
            a0 += b2f((unsigned short)w4); a1 += b2f((unsigned short)(w4 >> 16));
            a0 += b2f((unsigned short)w5); a1 += b2f((unsigned short)(w5 >> 16));
            a0 += b2f((unsigned short)w6); a1 += b2f((unsigned short)(w6 >> 16));
            a0 += b2f((unsigned short)w7); a1 += b2f((unsigned short)(w7 >> 16));
        }
        for (; j < c; j++){
            int s = __builtin_nontemporal_load(csr + start + j);
            unsigned v = *(const unsigned*)(tab + (size_t)s * 16 + sub * 2);
            a0 += b2f((unsigned short)v);
            a1 += b2f((unsigned short)(v >> 16));
        }
        float r0 = fmaf(dv, a0, bb.x);
        float r1 = fmaf(dv, a1, bb.y);
        *(unsigned*)(z2 + (size_t)node * 64 + slice * 16 + sub * 2) =
            (unsigned)f2b(r0) | ((unsigned)f2b(r1) << 16);
    }
}

// ------- decode: out[e] = dot(z2[s], z2[t]); 4 edges/wave, uint2 loads ---------
__global__ __launch_bounds__(256) void k_decode(const unsigned short* __restrict__ z,
                                                const int* __restrict__ es,
                                                const int* __restrict__ et,
                                                float* __restrict__ out, int m){
    int wv = (blockIdx.x * 256 + threadIdx.x) >> 6;
    int lane = threadIdx.x & 63;
    int e = wv * 4 + (lane >> 4);
    int ql = lane & 15;
    float p = 0.f;
    if (e < m){
        size_t s = (size_t)es[e], t2 = (size_t)et[e];
        uint2 vs = *(const uint2*)(z + s * 64 + ql * 4);
        uint2 vt = *(const uint2*)(z + t2 * 64 + ql * 4);
        p = b2f((unsigned short)vs.x) * b2f((unsigned short)vt.x)
          + b2f((unsigned short)(vs.x >> 16)) * b2f((unsigned short)(vt.x >> 16))
          + b2f((unsigned short)vs.y) * b2f((unsigned short)vt.y)
          + b2f((unsigned short)(vs.y >> 16)) * b2f((unsigned short)(vt.y >> 16));
    }
    #pragma unroll
    for (int o = 8; o > 0; o >>= 1) p += __shfl_xor(p, o);
    if (ql == 0 && e < m) out[e] = p;
}

// ---------------- launcher ----------------

extern "C" void kernel_launch(void* const* d_in, const int* in_sizes, int n_in,
                              void* d_out, int out_size, void* d_ws, size_t ws_size,
                              hipStream_t stream){
    const float* x   = (const float*)d_in[0];
    const int*   ei  = (const int*)d_in[1];
    const int*   eli = (const int*)d_in[2];
    const float* W1  = (const float*)d_in[3];
    const float* b1  = (const float*)d_in[4];
    const float* W2  = (const float*)d_in[5];
    const float* b2  = (const float*)d_in[6];
    float* out = (float*)d_out;

    int N_  = in_sizes[0] / 128;
    int E_  = in_sizes[1] / 2;
    int EL_ = in_sizes[2] / 2;
    int NBINS = (N_ + 127) >> 7;           // 782 for N=100k (must be <= 1024)
    const int EPB = 8192;
    int NBLK = (E_ + EPB - 1) / EPB;       // 196 for E=1.6M

    char* w = (char*)d_ws;
    size_t o = 0;
    auto alloc = [&](size_t bytes) -> size_t {
        size_t r = o; o += (bytes + 511) & ~(size_t)511; return r;
    };
    size_t o_cnt  = alloc((size_t)N_ * 4);
    size_t o_off  = alloc((size_t)N_ * 4);
    size_t o_dinv = alloc((size_t)N_ * 4);
    size_t o_gcur = alloc((size_t)NBINS * 4);
    size_t o_boff = alloc((size_t)(NBINS + 1) * 4);
    size_t o_csr  = alloc((size_t)E_ * 4);
    size_t o_wf1  = alloc(16384 * 2);
    size_t o_wf2  = alloc(8192 * 2);
    size_t o_hs1  = alloc((size_t)N_ * 128 * 2);   // 25.6MB; also slab, hs2cb, z2
    size_t o_z1   = alloc((size_t)N_ * 128 * 2);   // z1cb 25.6MB

    int* cnt  = (int*)(w + o_cnt);
    int* off  = (int*)(w + o_off);
    float* dinv = (float*)(w + o_dinv);
    int* gcur = (int*)(w + o_gcur);
    int* boff = (int*)(w + o_boff);
    int* csr  = (int*)(w + o_csr);
    unsigned short* wf1 = (unsigned short*)(w + o_wf1);
    unsigned short* wf2 = (unsigned short*)(w + o_wf2);
    unsigned short* hs1 = (unsigned short*)(w + o_hs1);            // hs1cb [8][N][16]
    unsigned short* z1  = (unsigned short*)(w + o_z1);             // z1cb  [8][N][16]
    // after k_cagg1, hs1cb region is dead -> reuse for hs2cb and z2:
    unsigned short* hs2 = (unsigned short*)(w + o_hs1);                          // [4][N][16], 12.8MB
    unsigned short* z2  = (unsigned short*)(w + o_hs1 + (size_t)N_ * 64 * 2);    // [N][64],    12.8MB
    // slab aliases hs1cb region (dead until k_gemm1): NBINS*4096*4 = 12.8MB
    unsigned* slab = (unsigned*)(w + o_hs1);

    const int GBLK = 2048;     // gather grids (multiple of 8)

    (void)hipMemsetAsync(gcur, 0, (size_t)NBINS * 4, stream);
    k_scatter2<<<NBLK, 256, 0, stream>>>(ei, ei + E_, gcur, slab, E_, NBINS);
    k_binscanB<<<1, 1024, 0, stream>>>(gcur, boff, NBINS);
    k_binsort <<<NBINS, 256, 0, stream>>>(slab, boff, csr, cnt, off, dinv, N_, NBINS);
    k_wconv   <<<12, 256, 0, stream>>>(W1, W2, wf1, wf2);
    k_gemm1   <<<(N_ + 63) / 64, 256, 0, stream>>>(x, wf1, dinv, hs1, N_);
    k_cagg1   <<<GBLK, 256, 0, stream>>>(hs1, off, cnt, csr, dinv, b1, z1, N_, GBLK);
    k_gemm2   <<<(N_ + 63) / 64, 256, 0, stream>>>(z1, wf2, dinv, hs2, N_);
    k_cagg2   <<<GBLK, 256, 0, stream>>>(hs2, off, cnt, csr, dinv, b2, z2, N_, GBLK);
    k_decode  <<<(EL_ + 15) / 16, 256, 0, stream>>>(z2, eli, eli + EL_, out, EL_);
}

// Round 11
// 283.416 us; speedup vs baseline: 1.4420x; 1.4420x over previous
//
#include <hip/hip_runtime.h>
#include <stdint.h>

typedef __bf16 bf16x8 __attribute__((ext_vector_type(8)));
typedef float  floatx4 __attribute__((ext_vector_type(4)));
typedef __fp16 h2 __attribute__((ext_vector_type(2)));

__device__ __forceinline__ unsigned short f2b(float x){
    unsigned u = __float_as_uint(x);
    u = u + 0x7FFFu + ((u >> 16) & 1u);          // RNE
    return (unsigned short)(u >> 16);
}
__device__ __forceinline__ float b2f(unsigned short h){
    return __uint_as_float(((unsigned)h) << 16);
}

// ================= CSR build: reservation counting sort =======================
// bin = dst >> 7 (128 nodes/bin). Slab capacity 4096/bin (mean 2046, sigma~45).

__global__ __launch_bounds__(256) void k_scatter2(const int* __restrict__ src,
                                                  const int* __restrict__ dst,
                                                  int* __restrict__ gcur,
                                                  unsigned* __restrict__ slab,
                                                  int E_, int nbins){
    __shared__ int h[1024];
    int t = threadIdx.x, blk = blockIdx.x;
    for (int i = t; i < nbins; i += 256) h[i] = 0;
    __syncthreads();
    int base = blk * 8192;
    #pragma unroll
    for (int j = 0; j < 8; j++){
        int e = base + (j * 256 + t) * 4;
        if (e < E_){
            int4 d = *(const int4*)(dst + e);
            atomicAdd(&h[d.x >> 7], 1);
            atomicAdd(&h[d.y >> 7], 1);
            atomicAdd(&h[d.z >> 7], 1);
            atomicAdd(&h[d.w >> 7], 1);
        }
    }
    __syncthreads();
    for (int i = t; i < nbins; i += 256){
        int hv = h[i];
        h[i] = hv ? atomicAdd(&gcur[i], hv) : 0;
    }
    __syncthreads();
    #pragma unroll
    for (int j = 0; j < 8; j++){
        int e = base + (j * 256 + t) * 4;
        if (e < E_){
            int4 d = *(const int4*)(dst + e);
            int4 s = *(const int4*)(src + e);
            int p0 = atomicAdd(&h[d.x >> 7], 1);
            slab[(size_t)(d.x >> 7) * 4096 + p0] = ((unsigned)(d.x & 127) << 25) | (unsigned)s.x;
            int p1 = atomicAdd(&h[d.y >> 7], 1);
            slab[(size_t)(d.y >> 7) * 4096 + p1] = ((unsigned)(d.y & 127) << 25) | (unsigned)s.y;
            int p2 = atomicAdd(&h[d.z >> 7], 1);
            slab[(size_t)(d.z >> 7) * 4096 + p2] = ((unsigned)(d.z & 127) << 25) | (unsigned)s.z;
            int p3 = atomicAdd(&h[d.w >> 7], 1);
            slab[(size_t)(d.w >> 7) * 4096 + p3] = ((unsigned)(d.w & 127) << 25) | (unsigned)s.w;
        }
    }
}

__global__ __launch_bounds__(1024) void k_binscanB(const int* __restrict__ btot,
                                                   int* __restrict__ boff, int nbins){
    __shared__ int s[1024];
    int t = threadIdx.x;
    s[t] = (t < nbins) ? btot[t] : 0;
    __syncthreads();
    for (int o = 1; o < 1024; o <<= 1){
        int v = (t >= o) ? s[t - o] : 0;
        __syncthreads();
        s[t] += v;
        __syncthreads();
    }
    if (t == 0) boff[0] = 0;
    if (t < nbins) boff[t + 1] = s[t];
}

__global__ __launch_bounds__(256) void k_binsort(const unsigned* __restrict__ slab,
                                                 const int* __restrict__ boff,
                                                 int* __restrict__ csr,
                                                 int* __restrict__ cnt,
                                                 int* __restrict__ off,
                                                 float* __restrict__ dinv,
                                                 int n, int nbins){
    int b = blockIdx.x, t = threadIdx.x;
    int s0 = boff[b], len = boff[b + 1] - s0;
    if (len > 4096) len = 4096;
    const unsigned* seg = slab + (size_t)b * 4096;
    __shared__ int cl[128], sc[128], cur[128];
    __shared__ unsigned buf[4096], outb[4096];
    if (t < 128){ cl[t] = 0; cur[t] = 0; }
    __syncthreads();
    for (int i = t; i < len; i += 256) buf[i] = seg[i];
    __syncthreads();
    for (int i = t; i < len; i += 256) atomicAdd(&cl[buf[i] >> 25], 1);
    __syncthreads();
    if (t < 128) sc[t] = cl[t];
    __syncthreads();
    for (int o = 1; o < 128; o <<= 1){
        int v = 0;
        if (t < 128 && t >= o) v = sc[t - o];
        __syncthreads();
        if (t < 128) sc[t] += v;
        __syncthreads();
    }
    for (int i = t; i < len; i += 256){
        unsigned w = buf[i];
        int nd = (int)(w >> 25);
        int p = (sc[nd] - cl[nd]) + atomicAdd(&cur[nd], 1);
        outb[p] = w & 0x1FFFFFFu;
    }
    __syncthreads();
    for (int i = t; i < len; i += 256) csr[s0 + i] = (int)outb[i];
    if (t < 128){
        int node = b * 128 + t;
        if (node < n){
            cnt[node] = cl[t];
            off[node] = s0 + (sc[t] - cl[t]);
            dinv[node] = rsqrtf((float)cl[t] + 1.0f);
        }
    }
}

// -------- weight prep: W1 -> MFMA B-frag order; W2 -> packed f16 pairs --------
__global__ __launch_bounds__(256) void k_wconv(const float* __restrict__ W1,
                                               const float* __restrict__ W2,
                                               unsigned short* __restrict__ wf1,
                                               unsigned* __restrict__ w2p){
    int f = blockIdx.x * 256 + threadIdx.x;
    if (f < 2048){
        int lane = f & 63;
        int ctkc = f >> 6;
        int kc = ctkc & 3, ct = ctkc >> 2;
        int col = ct * 16 + (lane & 15);
        int k0  = kc * 32 + (lane >> 4) * 8;
        unsigned short* d = wf1 + (size_t)f * 8;
        #pragma unroll
        for (int j = 0; j < 8; j++) d[j] = f2b(W1[(k0 + j) * 128 + col]);
    } else if (f < 2048 + 4096){
        int lf = f - 2048;
        int kp = lf >> 6, lane = lf & 63;
        h2 p = __builtin_amdgcn_cvt_pkrtz(W2[(2 * kp) * 64 + lane],
                                          W2[(2 * kp + 1) * 64 + lane]);
        w2p[lf] = __builtin_bit_cast(unsigned, p);
    }
}

// ---------------- GEMM1: hs1 = bf16( (x @ W1) * dinv[row] ), row-major --------
__global__ __launch_bounds__(256) void k_gemm1(const float* __restrict__ x,
                                               const unsigned short* __restrict__ wf,
                                               const float* __restrict__ dinv,
                                               unsigned short* __restrict__ hs, int n){
    __shared__ unsigned short Wl[16384];
    __shared__ unsigned short Al[64 * 136];
    int t = threadIdx.x;
    long rowBase = (long)blockIdx.x * 64;
    {
        const uint4* s4 = (const uint4*)wf;
        uint4* d4 = (uint4*)Wl;
        #pragma unroll
        for (int i = 0; i < 8; i++) d4[t + i * 256] = s4[t + i * 256];
    }
    {
        const float4* xs = (const float4*)(x + rowBase * 128);
        #pragma unroll
        for (int k = 0; k < 8; k++){
            int i = t + k * 256;
            int r = i >> 5, c4 = (i & 31) << 2;
            float4 v = make_float4(0.f, 0.f, 0.f, 0.f);
            if (rowBase + r < n) v = xs[i];
            unsigned lo = (unsigned)f2b(v.x) | ((unsigned)f2b(v.y) << 16);
            unsigned hi = (unsigned)f2b(v.z) | ((unsigned)f2b(v.w) << 16);
            *(uint2*)&Al[r * 136 + c4] = make_uint2(lo, hi);
        }
    }
    __syncthreads();
    int w = t >> 6, lane = t & 63, lr = lane & 15, q = lane >> 4;
    floatx4 zero = {0.f, 0.f, 0.f, 0.f};
    floatx4 acc[8];
    #pragma unroll
    for (int ct = 0; ct < 8; ct++) acc[ct] = zero;
    #pragma unroll
    for (int kc = 0; kc < 4; kc++){
        bf16x8 af = *(const bf16x8*)&Al[(w * 16 + lr) * 136 + kc * 32 + q * 8];
        #pragma unroll
        for (int ct = 0; ct < 8; ct++){
            bf16x8 bf = *(const bf16x8*)&Wl[((ct * 4 + kc) * 64 + lane) * 8];
            acc[ct] = __builtin_amdgcn_mfma_f32_16x16x32_bf16(af, bf, acc[ct], 0, 0, 0);
        }
    }
    long r0 = rowBase + w * 16 + q * 4;
    #pragma unroll
    for (int r = 0; r < 4; r++){
        long row = r0 + r;
        if (row >= n) continue;
        float dv = dinv[row];
        unsigned short* orow = hs + row * 128 + lr;
        #pragma unroll
        for (int ct = 0; ct < 8; ct++) orow[ct * 16] = f2b(acc[ct][r] * dv);
    }
}

// ---- fused agg1 + gemm2: hs2[i] = bf16( (relu(dinv_i*(sum hs1[src]+hs1[i])+b1) @ W2) * dinv_i )
// wave per node, uint2 gather (8B/lane): 2 rows per load (half-wave per row),
// shfl_xor(32) combine; projection via v_dot2_f32_f16 (packed f16 W2 in LDS).
__global__ __launch_bounds__(256) void k_agg1g2(const unsigned short* __restrict__ hs,
                                                const int* __restrict__ off,
                                                const int* __restrict__ cnt,
                                                const int* __restrict__ csr,
                                                const float* __restrict__ dinv,
                                                const float* __restrict__ b1,
                                                const unsigned* __restrict__ w2p,
                                                unsigned short* __restrict__ hs2,
                                                int n, int nwaves){
    __shared__ unsigned W2l[4096];     // 16 KB packed half2 [kp][lane]
    __shared__ unsigned zp[4][64];     // packed half2 z row per wave
    int t = threadIdx.x;
    {
        const uint4* w4 = (const uint4*)w2p;
        uint4* d4 = (uint4*)W2l;
        #pragma unroll
        for (int i = 0; i < 4; i++) d4[t + i * 256] = w4[t + i * 256];
    }
    __syncthreads();
    int wband = t >> 6, lane = t & 63;
    int half = lane >> 5, hl = lane & 31;      // cols hl*4 .. hl*4+3
    float4 bb = ((const float4*)b1)[hl];
    for (int wid = blockIdx.x * 4 + wband; wid < n; wid += nwaves){
        size_t i = (size_t)wid;
        int start = off[wid], c = cnt[wid];
        float a0 = 0.f, a1 = 0.f, a2 = 0.f, a3 = 0.f;
        int j = 0;
        for (; j + 16 <= c; j += 16){
            int i0 = csr[start + j +  0 + half];
            int i1 = csr[start + j +  2 + half];
            int i2 = csr[start + j +  4 + half];
            int i3 = csr[start + j +  6 + half];
            int i4 = csr[start + j +  8 + half];
            int i5 = csr[start + j + 10 + half];
            int i6 = csr[start + j + 12 + half];
            int i7 = csr[start + j + 14 + half];
            uint2 w0 = *(const uint2*)(hs + (size_t)i0 * 128 + hl * 4);
            uint2 w1 = *(const uint2*)(hs + (size_t)i1 * 128 + hl * 4);
            uint2 w2 = *(const uint2*)(hs + (size_t)i2 * 128 + hl * 4);
            uint2 w3 = *(const uint2*)(hs + (size_t)i3 * 128 + hl * 4);
            uint2 w4 = *(const uint2*)(hs + (size_t)i4 * 128 + hl * 4);
            uint2 w5 = *(const uint2*)(hs + (size_t)i5 * 128 + hl * 4);
            uint2 w6 = *(const uint2*)(hs + (size_t)i6 * 128 + hl * 4);
            uint2 w7 = *(const uint2*)(hs + (size_t)i7 * 128 + hl * 4);
            a0 += b2f((unsigned short)w0.x); a1 += b2f((unsigned short)(w0.x >> 16));
            a2 += b2f((unsigned short)w0.y); a3 += b2f((unsigned short)(w0.y >> 16));
            a0 += b2f((unsigned short)w1.x); a1 += b2f((unsigned short)(w1.x >> 16));
            a2 += b2f((unsigned short)w1.y); a3 += b2f((unsigned short)(w1.y >> 16));
            a0 += b2f((unsigned short)w2.x); a1 += b2f((unsigned short)(w2.x >> 16));
            a2 += b2f((unsigned short)w2.y); a3 += b2f((unsigned short)(w2.y >> 16));
            a0 += b2f((unsigned short)w3.x); a1 += b2f((unsigned short)(w3.x >> 16));
            a2 += b2f((unsigned short)w3.y); a3 += b2f((unsigned short)(w3.y >> 16));
            a0 += b2f((unsigned short)w4.x); a1 += b2f((unsigned short)(w4.x >> 16));
            a2 += b2f((unsigned short)w4.y); a3 += b2f((unsigned short)(w4.y >> 16));
            a0 += b2f((unsigned short)w5.x); a1 += b2f((unsigned short)(w5.x >> 16));
            a2 += b2f((unsigned short)w5.y); a3 += b2f((unsigned short)(w5.y >> 16));
            a0 += b2f((unsigned short)w6.x); a1 += b2f((unsigned short)(w6.x >> 16));
            a2 += b2f((unsigned short)w6.y); a3 += b2f((unsigned short)(w6.y >> 16));
            a0 += b2f((unsigned short)w7.x); a1 += b2f((unsigned short)(w7.x >> 16));
            a2 += b2f((unsigned short)w7.y); a3 += b2f((unsigned short)(w7.y >> 16));
        }
        for (; j + 2 <= c; j += 2){
            int s = csr[start + j + half];
            uint2 v = *(const uint2*)(hs + (size_t)s * 128 + hl * 4);
            a0 += b2f((unsigned short)v.x); a1 += b2f((unsigned short)(v.x >> 16));
            a2 += b2f((unsigned short)v.y); a3 += b2f((unsigned short)(v.y >> 16));
        }
        if (j < c && half == 0){
            int s = csr[start + j];
            uint2 v = *(const uint2*)(hs + (size_t)s * 128 + hl * 4);
            a0 += b2f((unsigned short)v.x); a1 += b2f((unsigned short)(v.x >> 16));
            a2 += b2f((unsigned short)v.y); a3 += b2f((unsigned short)(v.y >> 16));
        }
        // combine halves (cols identical across halves)
        a0 += __shfl_xor(a0, 32);
        a1 += __shfl_xor(a1, 32);
        a2 += __shfl_xor(a2, 32);
        a3 += __shfl_xor(a3, 32);
        // self row
        uint2 sv = *(const uint2*)(hs + i * 128 + hl * 4);
        a0 += b2f((unsigned short)sv.x); a1 += b2f((unsigned short)(sv.x >> 16));
        a2 += b2f((unsigned short)sv.y); a3 += b2f((unsigned short)(sv.y >> 16));
        float dv = dinv[wid];
        float z0 = fmaxf(fmaf(dv, a0, bb.x), 0.f);
        float z1 = fmaxf(fmaf(dv, a1, bb.y), 0.f);
        float z2 = fmaxf(fmaf(dv, a2, bb.z), 0.f);
        float z3 = fmaxf(fmaf(dv, a3, bb.w), 0.f);
        if (half == 0){
            zp[wband][2 * hl]     = __builtin_bit_cast(unsigned, __builtin_amdgcn_cvt_pkrtz(z0, z1));
            zp[wband][2 * hl + 1] = __builtin_bit_cast(unsigned, __builtin_amdgcn_cvt_pkrtz(z2, z3));
        }
        float acc0 = 0.f, acc1 = 0.f;
        #pragma unroll 8
        for (int kp = 0; kp < 64; kp += 2){
            h2 wa = __builtin_bit_cast(h2, W2l[kp * 64 + lane]);
            h2 wb = __builtin_bit_cast(h2, W2l[(kp + 1) * 64 + lane]);
            h2 za = __builtin_bit_cast(h2, zp[wband][kp]);
            h2 zb = __builtin_bit_cast(h2, zp[wband][kp + 1]);
            acc0 = __builtin_amdgcn_fdot2(za, wa, acc0, false);
            acc1 = __builtin_amdgcn_fdot2(zb, wb, acc1, false);
        }
        hs2[i * 64 + lane] = f2b((acc0 + acc1) * dv);
    }
}

// -------- aggregation layer 2: wave per node, uint2 gather (4 rows/load) -------
// lane: g = lane>>4 (neighbor group), q = lane&15 (cols q*4..+3).
__global__ __launch_bounds__(256) void k_agg2(const unsigned short* __restrict__ hs,
                                              const int* __restrict__ off,
                                              const int* __restrict__ cnt,
                                              const int* __restrict__ csr,
                                              const float* __restrict__ dinv,
                                              const float* __restrict__ b,
                                              unsigned short* __restrict__ z, int n){
    int node = (blockIdx.x * 256 + threadIdx.x) >> 6;
    int lane = threadIdx.x & 63;
    if (node >= n) return;
    int g = lane >> 4, q = lane & 15;
    size_t i = (size_t)node;
    int start = off[node], c = cnt[node];
    float a0 = 0.f, a1 = 0.f, a2 = 0.f, a3 = 0.f;
    int j = 0;
    for (; j + 16 <= c; j += 16){
        int i0 = csr[start + j +  0 + g];
        int i1 = csr[start + j +  4 + g];
        int i2 = csr[start + j +  8 + g];
        int i3 = csr[start + j + 12 + g];
        uint2 w0 = *(const uint2*)(hs + (size_t)i0 * 64 + q * 4);
        uint2 w1 = *(const uint2*)(hs + (size_t)i1 * 64 + q * 4);
        uint2 w2 = *(const uint2*)(hs + (size_t)i2 * 64 + q * 4);
        uint2 w3 = *(const uint2*)(hs + (size_t)i3 * 64 + q * 4);
        a0 += b2f((unsigned short)w0.x); a1 += b2f((unsigned short)(w0.x >> 16));
        a2 += b2f((unsigned short)w0.y); a3 += b2f((unsigned short)(w0.y >> 16));
        a0 += b2f((unsigned short)w1.x); a1 += b2f((unsigned short)(w1.x >> 16));
        a2 += b2f((unsigned short)w1.y); a3 += b2f((unsigned short)(w1.y >> 16));
        a0 += b2f((unsigned short)w2.x); a1 += b2f((unsigned short)(w2.x >> 16));
        a2 += b2f((unsigned short)w2.y); a3 += b2f((unsigned short)(w2.y >> 16));
        a0 += b2f((unsigned short)w3.x); a1 += b2f((unsigned short)(w3.x >> 16));
        a2 += b2f((unsigned short)w3.y); a3 += b2f((unsigned short)(w3.y >> 16));
    }
    for (; j + 4 <= c; j += 4){
        int s = csr[start + j + g];
        uint2 v = *(const uint2*)(hs + (size_t)s * 64 + q * 4);
        a0 += b2f((unsigned short)v.x); a1 += b2f((unsigned short)(v.x >> 16));
        a2 += b2f((unsigned short)v.y); a3 += b2f((unsigned short)(v.y >> 16));
    }
    int rem = c - j;
    if (g < rem){
        int s = csr[start + j + g];
        uint2 v = *(const uint2*)(hs + (size_t)s * 64 + q * 4);
        a0 += b2f((unsigned short)v.x); a1 += b2f((unsigned short)(v.x >> 16));
        a2 += b2f((unsigned short)v.y); a3 += b2f((unsigned short)(v.y >> 16));
    }
    // combine 4 groups (cols identical across groups)
    a0 += __shfl_xor(a0, 16); a1 += __shfl_xor(a1, 16);
    a2 += __shfl_xor(a2, 16); a3 += __shfl_xor(a3, 16);
    a0 += __shfl_xor(a0, 32); a1 += __shfl_xor(a1, 32);
    a2 += __shfl_xor(a2, 32); a3 += __shfl_xor(a3, 32);
    // self row
    uint2 sv = *(const uint2*)(hs + i * 64 + q * 4);
    a0 += b2f((unsigned short)sv.x); a1 += b2f((unsigned short)(sv.x >> 16));
    a2 += b2f((unsigned short)sv.y); a3 += b2f((unsigned short)(sv.y >> 16));
    float dv = dinv[node];
    float4 bb = ((const float4*)b)[q];
    if (g == 0){
        unsigned lo = (unsigned)f2b(fmaf(dv, a0, bb.x)) | ((unsigned)f2b(fmaf(dv, a1, bb.y)) << 16);
        unsigned hi = (unsigned)f2b(fmaf(dv, a2, bb.z)) | ((unsigned)f2b(fmaf(dv, a3, bb.w)) << 16);
        *(uint2*)(z + i * 64 + q * 4) = make_uint2(lo, hi);
    }
}

// ------- decode: out[e] = dot(z2[s], z2[t]); 4 edges/wave, uint2 loads ---------
__global__ __launch_bounds__(256) void k_decode(const unsigned short* __restrict__ z,
                                                const int* __restrict__ es,
                                                const int* __restrict__ et,
                                                float* __restrict__ out, int m){
    int wv = (blockIdx.x * 256 + threadIdx.x) >> 6;
    int lane = threadIdx.x & 63;
    int e = wv * 4 + (lane >> 4);
    int ql = lane & 15;
    float p = 0.f;
    if (e < m){
        size_t s = (size_t)es[e], t2 = (size_t)et[e];
        uint2 vs = *(const uint2*)(z + s * 64 + ql * 4);
        uint2 vt = *(const uint2*)(z + t2 * 64 + ql * 4);
        p = b2f((unsigned short)vs.x) * b2f((unsigned short)vt.x)
          + b2f((unsigned short)(vs.x >> 16)) * b2f((unsigned short)(vt.x >> 16))
          + b2f((unsigned short)vs.y) * b2f((unsigned short)vt.y)
          + b2f((unsigned short)(vs.y >> 16)) * b2f((unsigned short)(vt.y >> 16));
    }
    #pragma unroll
    for (int o = 8; o > 0; o >>= 1) p += __shfl_xor(p, o);
    if (ql == 0 && e < m) out[e] = p;
}

// ---------------- launcher ----------------

extern "C" void kernel_launch(void* const* d_in, const int* in_sizes, int n_in,
                              void* d_out, int out_size, void* d_ws, size_t ws_size,
                              hipStream_t stream){
    const float* x   = (const float*)d_in[0];
    const int*   ei  = (const int*)d_in[1];
    const int*   eli = (const int*)d_in[2];
    const float* W1  = (const float*)d_in[3];
    const float* b1  = (const float*)d_in[4];
    const float* W2  = (const float*)d_in[5];
    const float* b2  = (const float*)d_in[6];
    float* out = (float*)d_out;

    int N_  = in_sizes[0] / 128;
    int E_  = in_sizes[1] / 2;
    int EL_ = in_sizes[2] / 2;
    int NBINS = (N_ + 127) >> 7;           // 782 for N=100k (must be <= 1024)
    const int EPB = 8192;
    int NBLK = (E_ + EPB - 1) / EPB;       // 196 for E=1.6M

    char* w = (char*)d_ws;
    size_t o = 0;
    auto alloc = [&](size_t bytes) -> size_t {
        size_t r = o; o += (bytes + 511) & ~(size_t)511; return r;
    };
    size_t o_cnt  = alloc((size_t)N_ * 4);
    size_t o_off  = alloc((size_t)N_ * 4);
    size_t o_dinv = alloc((size_t)N_ * 4);
    size_t o_gcur = alloc((size_t)NBINS * 4);
    size_t o_boff = alloc((size_t)(NBINS + 1) * 4);
    size_t o_csr  = alloc((size_t)E_ * 4);
    size_t o_wf1  = alloc(16384 * 2);
    size_t o_w2p  = alloc(4096 * 4);
    size_t o_hs1  = alloc((size_t)N_ * 128 * 2);   // 25.6MB; also hosts slab & z2
    size_t o_hs2  = alloc((size_t)N_ * 64 * 2);

    int* cnt  = (int*)(w + o_cnt);
    int* off  = (int*)(w + o_off);
    float* dinv = (float*)(w + o_dinv);
    int* gcur = (int*)(w + o_gcur);
    int* boff = (int*)(w + o_boff);
    int* csr  = (int*)(w + o_csr);
    unsigned short* wf1 = (unsigned short*)(w + o_wf1);
    unsigned* w2p = (unsigned*)(w + o_w2p);
    unsigned short* hs1 = (unsigned short*)(w + o_hs1);
    unsigned short* hs2 = (unsigned short*)(w + o_hs2);
    unsigned short* z2  = (unsigned short*)(w + o_hs1);  // hs1 dead after agg1g2

    // slab aliases the hs1 region (dead until k_gemm1 writes hs1):
    // NBINS*4096*4B = 12.8MB <= 25.6MB
    unsigned* slab = (unsigned*)(w + o_hs1);

    const int AGG1_BLOCKS = 2048;          // 8 blocks/CU (18KB LDS) -> 32 waves/CU
    int nwaves = AGG1_BLOCKS * 4;

    (void)hipMemsetAsync(gcur, 0, (size_t)NBINS * 4, stream);
    k_scatter2<<<NBLK, 256, 0, stream>>>(ei, ei + E_, gcur, slab, E_, NBINS);
    k_binscanB<<<1, 1024, 0, stream>>>(gcur, boff, NBINS);
    k_binsort <<<NBINS, 256, 0, stream>>>(slab, boff, csr, cnt, off, dinv, N_, NBINS);
    k_wconv   <<<24, 256, 0, stream>>>(W1, W2, wf1, w2p);
    k_gemm1   <<<(N_ + 63) / 64, 256, 0, stream>>>(x, wf1, dinv, hs1, N_);
    k_agg1g2  <<<AGG1_BLOCKS, 256, 0, stream>>>(hs1, off, cnt, csr, dinv, b1, w2p, hs2, N_, nwaves);
    k_agg2    <<<(N_ + 3) / 4, 256, 0, stream>>>(hs2, off, cnt, csr, dinv, b2, z2, N_);
    k_decode  <<<(EL_ + 15) / 16, 256, 0, stream>>>(z2, eli, eli + EL_, out, EL_);
}

// Round 12
// 279.802 us; speedup vs baseline: 1.4606x; 1.0129x over previous
//
#include <hip/hip_runtime.h>
#include <stdint.h>

typedef __bf16 bf16x8 __attribute__((ext_vector_type(8)));
typedef float  floatx4 __attribute__((ext_vector_type(4)));
typedef __fp16 h2 __attribute__((ext_vector_type(2)));

__device__ __forceinline__ unsigned short f2b(float x){
    unsigned u = __float_as_uint(x);
    u = u + 0x7FFFu + ((u >> 16) & 1u);          // RNE
    return (unsigned short)(u >> 16);
}
__device__ __forceinline__ float b2f(unsigned short h){
    return __uint_as_float(((unsigned)h) << 16);
}

// ================= CSR build: reservation counting sort (single pass) =========
// bin = dst >> 7 (128 nodes/bin). Slab capacity 4096/bin (mean 2046, sigma~45).
// One pass over edges: pack words + bins into LDS, per-block LDS hist, one
// global atomicAdd per (block,bin) reserves slab space, then LDS->slab flush.
__global__ __launch_bounds__(256) void k_scatter2(const int* __restrict__ src,
                                                  const int* __restrict__ dst,
                                                  int* __restrict__ gcur,
                                                  unsigned* __restrict__ slab,
                                                  int E_, int nbins){
    __shared__ int h[1024];
    __shared__ unsigned wbuf[4096];
    __shared__ unsigned short bbuf[4096];
    int t = threadIdx.x, blk = blockIdx.x;
    for (int i = t; i < nbins; i += 256) h[i] = 0;
    __syncthreads();
    int base = blk * 4096;
    int valid = E_ - base; if (valid > 4096) valid = 4096;
    #pragma unroll
    for (int j = 0; j < 4; j++){
        int li = (j * 256 + t) * 4;
        int e = base + li;
        if (e < E_){
            int4 d = *(const int4*)(dst + e);
            int4 s = *(const int4*)(src + e);
            wbuf[li + 0] = ((unsigned)(d.x & 127) << 25) | (unsigned)s.x;
            wbuf[li + 1] = ((unsigned)(d.y & 127) << 25) | (unsigned)s.y;
            wbuf[li + 2] = ((unsigned)(d.z & 127) << 25) | (unsigned)s.z;
            wbuf[li + 3] = ((unsigned)(d.w & 127) << 25) | (unsigned)s.w;
            bbuf[li + 0] = (unsigned short)(d.x >> 7);
            bbuf[li + 1] = (unsigned short)(d.y >> 7);
            bbuf[li + 2] = (unsigned short)(d.z >> 7);
            bbuf[li + 3] = (unsigned short)(d.w >> 7);
            atomicAdd(&h[d.x >> 7], 1);
            atomicAdd(&h[d.y >> 7], 1);
            atomicAdd(&h[d.z >> 7], 1);
            atomicAdd(&h[d.w >> 7], 1);
        }
    }
    __syncthreads();
    for (int i = t; i < nbins; i += 256){
        int hv = h[i];
        h[i] = hv ? atomicAdd(&gcur[i], hv) : 0;
    }
    __syncthreads();
    for (int i = t; i < valid; i += 256){
        int bin = bbuf[i];
        int p = atomicAdd(&h[bin], 1);
        slab[(size_t)bin * 4096 + p] = wbuf[i];
    }
}

// one block per bin: computes its own boff prefix from gcur; local
// count/scan/rank in LDS; coalesced csr write; emits cnt/off/dinv.
__global__ __launch_bounds__(256) void k_binsort(const unsigned* __restrict__ slab,
                                                 const int* __restrict__ gcur,
                                                 int* __restrict__ csr,
                                                 int* __restrict__ cnt,
                                                 int* __restrict__ off,
                                                 float* __restrict__ dinv,
                                                 int n, int nbins){
    int b = blockIdx.x, t = threadIdx.x;
    __shared__ int sv[1024], sp[256];
    #pragma unroll
    for (int k = 0; k < 4; k++){
        int i = t * 4 + k;
        sv[i] = (i < nbins) ? gcur[i] : 0;
    }
    __syncthreads();
    int a0 = sv[t * 4], a1 = sv[t * 4 + 1], a2 = sv[t * 4 + 2], a3 = sv[t * 4 + 3];
    sp[t] = a0 + a1 + a2 + a3;
    __syncthreads();
    for (int o = 1; o < 256; o <<= 1){
        int v = (t >= o) ? sp[t - o] : 0;
        __syncthreads();
        sp[t] += v;
        __syncthreads();
    }
    int basep = t ? sp[t - 1] : 0;
    sv[t * 4]     = basep;
    sv[t * 4 + 1] = basep + a0;
    sv[t * 4 + 2] = basep + a0 + a1;
    sv[t * 4 + 3] = basep + a0 + a1 + a2;
    __syncthreads();
    int s0 = sv[b];
    int len = gcur[b];
    if (len > 4096) len = 4096;
    const unsigned* seg = slab + (size_t)b * 4096;
    __shared__ int cl[128], sc[128], cur[128];
    __shared__ unsigned buf[4096], outb[4096];
    if (t < 128){ cl[t] = 0; cur[t] = 0; }
    __syncthreads();
    for (int i = t; i < len; i += 256) buf[i] = seg[i];
    __syncthreads();
    for (int i = t; i < len; i += 256) atomicAdd(&cl[buf[i] >> 25], 1);
    __syncthreads();
    if (t < 128) sc[t] = cl[t];
    __syncthreads();
    for (int o = 1; o < 128; o <<= 1){
        int v = 0;
        if (t < 128 && t >= o) v = sc[t - o];
        __syncthreads();
        if (t < 128) sc[t] += v;
        __syncthreads();
    }
    for (int i = t; i < len; i += 256){
        unsigned w = buf[i];
        int nd = (int)(w >> 25);
        int p = (sc[nd] - cl[nd]) + atomicAdd(&cur[nd], 1);
        outb[p] = w & 0x1FFFFFFu;
    }
    __syncthreads();
    for (int i = t; i < len; i += 256) csr[s0 + i] = (int)outb[i];
    if (t < 128){
        int node = b * 128 + t;
        if (node < n){
            cnt[node] = cl[t];
            off[node] = s0 + (sc[t] - cl[t]);
            dinv[node] = rsqrtf((float)cl[t] + 1.0f);
        }
    }
}

// -------- weight prep: W1 -> MFMA B-frag order; W2 -> packed f16 pairs --------
__global__ __launch_bounds__(256) void k_wconv(const float* __restrict__ W1,
                                               const float* __restrict__ W2,
                                               unsigned short* __restrict__ wf1,
                                               unsigned* __restrict__ w2p){
    int f = blockIdx.x * 256 + threadIdx.x;
    if (f < 2048){
        int lane = f & 63;
        int ctkc = f >> 6;
        int kc = ctkc & 3, ct = ctkc >> 2;
        int col = ct * 16 + (lane & 15);
        int k0  = kc * 32 + (lane >> 4) * 8;
        unsigned short* d = wf1 + (size_t)f * 8;
        #pragma unroll
        for (int j = 0; j < 8; j++) d[j] = f2b(W1[(k0 + j) * 128 + col]);
    } else if (f < 2048 + 4096){
        int lf = f - 2048;
        int kp = lf >> 6, lane = lf & 63;
        h2 p = __builtin_amdgcn_cvt_pkrtz(W2[(2 * kp) * 64 + lane],
                                          W2[(2 * kp + 1) * 64 + lane]);
        w2p[lf] = __builtin_bit_cast(unsigned, p);
    }
}

// ---------------- GEMM1: hs1 = bf16( (x @ W1) * dinv[row] ) ----------------
__global__ __launch_bounds__(256) void k_gemm1(const float* __restrict__ x,
                                               const unsigned short* __restrict__ wf,
                                               const float* __restrict__ dinv,
                                               unsigned short* __restrict__ hs, int n){
    __shared__ unsigned short Wl[16384];
    __shared__ unsigned short Al[64 * 136];
    int t = threadIdx.x;
    long rowBase = (long)blockIdx.x * 64;
    {
        const uint4* s4 = (const uint4*)wf;
        uint4* d4 = (uint4*)Wl;
        #pragma unroll
        for (int i = 0; i < 8; i++) d4[t + i * 256] = s4[t + i * 256];
    }
    {
        const float4* xs = (const float4*)(x + rowBase * 128);
        #pragma unroll
        for (int k = 0; k < 8; k++){
            int i = t + k * 256;
            int r = i >> 5, c4 = (i & 31) << 2;
            float4 v = make_float4(0.f, 0.f, 0.f, 0.f);
            if (rowBase + r < n) v = xs[i];
            unsigned lo = (unsigned)f2b(v.x) | ((unsigned)f2b(v.y) << 16);
            unsigned hi = (unsigned)f2b(v.z) | ((unsigned)f2b(v.w) << 16);
            *(uint2*)&Al[r * 136 + c4] = make_uint2(lo, hi);
        }
    }
    __syncthreads();
    int w = t >> 6, lane = t & 63, lr = lane & 15, q = lane >> 4;
    floatx4 zero = {0.f, 0.f, 0.f, 0.f};
    floatx4 acc[8];
    #pragma unroll
    for (int ct = 0; ct < 8; ct++) acc[ct] = zero;
    #pragma unroll
    for (int kc = 0; kc < 4; kc++){
        bf16x8 af = *(const bf16x8*)&Al[(w * 16 + lr) * 136 + kc * 32 + q * 8];
        #pragma unroll
        for (int ct = 0; ct < 8; ct++){
            bf16x8 bf = *(const bf16x8*)&Wl[((ct * 4 + kc) * 64 + lane) * 8];
            acc[ct] = __builtin_amdgcn_mfma_f32_16x16x32_bf16(af, bf, acc[ct], 0, 0, 0);
        }
    }
    long r0 = rowBase + w * 16 + q * 4;
    #pragma unroll
    for (int r = 0; r < 4; r++){
        long row = r0 + r;
        if (row >= n) continue;
        float dv = dinv[row];
        unsigned short* orow = hs + row * 128 + lr;
        #pragma unroll
        for (int ct = 0; ct < 8; ct++) orow[ct * 16] = f2b(acc[ct][r] * dv);
    }
}

// ---- fused agg1 + gemm2: hs2[i] = bf16( (relu(dinv_i*(sum hs1[src]+hs1[i])+b1) @ W2) * dinv_i )
// wave per node (grid-stride, 2048 persistent blocks); projection via
// v_dot2_f32_f16 on packed f16 pairs, 2 independent accumulator chains.
__global__ __launch_bounds__(256) void k_agg1g2(const unsigned short* __restrict__ hs,
                                                const int* __restrict__ off,
                                                const int* __restrict__ cnt,
                                                const int* __restrict__ csr,
                                                const float* __restrict__ dinv,
                                                const float* __restrict__ b1,
                                                const unsigned* __restrict__ w2p,
                                                unsigned short* __restrict__ hs2,
                                                int n, int nwaves){
    __shared__ unsigned W2l[4096];     // 16 KB packed half2 [kp][lane]
    __shared__ unsigned zp[4][64];     // packed half2 z row per wave
    int t = threadIdx.x;
    {
        const uint4* w4 = (const uint4*)w2p;
        uint4* d4 = (uint4*)W2l;
        #pragma unroll
        for (int i = 0; i < 4; i++) d4[t + i * 256] = w4[t + i * 256];
    }
    __syncthreads();
    int wband = t >> 6, lane = t & 63;
    float2 bb = ((const float2*)b1)[lane];
    for (int wid = blockIdx.x * 4 + wband; wid < n; wid += nwaves){
        size_t i = (size_t)wid;
        int start = off[wid], c = cnt[wid];
        unsigned v0 = *(const unsigned*)(hs + i * 128 + lane * 2);
        float a0 = b2f((unsigned short)v0);
        float a1 = b2f((unsigned short)(v0 >> 16));
        int j = 0;
        for (; j + 8 <= c; j += 8){
            size_t s0 = (size_t)csr[start + j + 0];
            size_t s1 = (size_t)csr[start + j + 1];
            size_t s2 = (size_t)csr[start + j + 2];
            size_t s3 = (size_t)csr[start + j + 3];
            size_t s4 = (size_t)csr[start + j + 4];
            size_t s5 = (size_t)csr[start + j + 5];
            size_t s6 = (size_t)csr[start + j + 6];
            size_t s7 = (size_t)csr[start + j + 7];
            unsigned w0 = *(const unsigned*)(hs + s0 * 128 + lane * 2);
            unsigned w1 = *(const unsigned*)(hs + s1 * 128 + lane * 2);
            unsigned w2 = *(const unsigned*)(hs + s2 * 128 + lane * 2);
            unsigned w3 = *(const unsigned*)(hs + s3 * 128 + lane * 2);
            unsigned w4 = *(const unsigned*)(hs + s4 * 128 + lane * 2);
            unsigned w5 = *(const unsigned*)(hs + s5 * 128 + lane * 2);
            unsigned w6 = *(const unsigned*)(hs + s6 * 128 + lane * 2);
            unsigned w7 = *(const unsigned*)(hs + s7 * 128 + lane * 2);
            a0 += b2f((unsigned short)w0); a1 += b2f((unsigned short)(w0 >> 16));
            a0 += b2f((unsigned short)w1); a1 += b2f((unsigned short)(w1 >> 16));
            a0 += b2f((unsigned short)w2); a1 += b2f((unsigned short)(w2 >> 16));
            a0 += b2f((unsigned short)w3); a1 += b2f((unsigned short)(w3 >> 16));
            a0 += b2f((unsigned short)w4); a1 += b2f((unsigned short)(w4 >> 16));
            a0 += b2f((unsigned short)w5); a1 += b2f((unsigned short)(w5 >> 16));
            a0 += b2f((unsigned short)w6); a1 += b2f((unsigned short)(w6 >> 16));
            a0 += b2f((unsigned short)w7); a1 += b2f((unsigned short)(w7 >> 16));
        }
        for (; j < c; j++){
            size_t s = (size_t)csr[start + j];
            unsigned v = *(const unsigned*)(hs + s * 128 + lane * 2);
            a0 += b2f((unsigned short)v);
            a1 += b2f((unsigned short)(v >> 16));
        }
        float dv = dinv[wid];
        float z0 = fmaxf(fmaf(dv, a0, bb.x), 0.f);
        float z1 = fmaxf(fmaf(dv, a1, bb.y), 0.f);
        // wave-synchronous LDS round trip (per-wave buffer, no barrier)
        zp[wband][lane] = __builtin_bit_cast(unsigned, __builtin_amdgcn_cvt_pkrtz(z0, z1));
        float acc0 = 0.f, acc1 = 0.f;
        #pragma unroll 8
        for (int kp = 0; kp < 64; kp += 2){
            h2 wa = __builtin_bit_cast(h2, W2l[kp * 64 + lane]);
            h2 wb = __builtin_bit_cast(h2, W2l[(kp + 1) * 64 + lane]);
            h2 za = __builtin_bit_cast(h2, zp[wband][kp]);
            h2 zb = __builtin_bit_cast(h2, zp[wband][kp + 1]);
            acc0 = __builtin_amdgcn_fdot2(za, wa, acc0, false);
            acc1 = __builtin_amdgcn_fdot2(zb, wb, acc1, false);
        }
        hs2[i * 64 + lane] = f2b((acc0 + acc1) * dv);
    }
}

// -------- aggregation layer 2: 2 nodes/wave (half-wave each), dword loads ------
__global__ __launch_bounds__(256) void k_agg2(const unsigned short* __restrict__ hs,
                                              const int* __restrict__ off,
                                              const int* __restrict__ cnt,
                                              const int* __restrict__ csr,
                                              const float* __restrict__ dinv,
                                              const float* __restrict__ b,
                                              unsigned short* __restrict__ z, int n){
    int wv = (blockIdx.x * 256 + threadIdx.x) >> 6;
    int lane = threadIdx.x & 63;
    int half = lane >> 5, hl = lane & 31;
    int node = wv * 2 + half;
    if (node >= n) return;
    size_t i = (size_t)node;
    int start = off[node], c = cnt[node];
    unsigned v0 = *(const unsigned*)(hs + i * 64 + hl * 2);
    float a0 = b2f((unsigned short)v0);
    float a1 = b2f((unsigned short)(v0 >> 16));
    int j = 0;
    for (; j + 8 <= c; j += 8){
        size_t s0 = (size_t)csr[start + j + 0];
        size_t s1 = (size_t)csr[start + j + 1];
        size_t s2 = (size_t)csr[start + j + 2];
        size_t s3 = (size_t)csr[start + j + 3];
        size_t s4 = (size_t)csr[start + j + 4];
        size_t s5 = (size_t)csr[start + j + 5];
        size_t s6 = (size_t)csr[start + j + 6];
        size_t s7 = (size_t)csr[start + j + 7];
        unsigned w0 = *(const unsigned*)(hs + s0 * 64 + hl * 2);
        unsigned w1 = *(const unsigned*)(hs + s1 * 64 + hl * 2);
        unsigned w2 = *(const unsigned*)(hs + s2 * 64 + hl * 2);
        unsigned w3 = *(const unsigned*)(hs + s3 * 64 + hl * 2);
        unsigned w4 = *(const unsigned*)(hs + s4 * 64 + hl * 2);
        unsigned w5 = *(const unsigned*)(hs + s5 * 64 + hl * 2);
        unsigned w6 = *(const unsigned*)(hs + s6 * 64 + hl * 2);
        unsigned w7 = *(const unsigned*)(hs + s7 * 64 + hl * 2);
        a0 += b2f((unsigned short)w0); a1 += b2f((unsigned short)(w0 >> 16));
        a0 += b2f((unsigned short)w1); a1 += b2f((unsigned short)(w1 >> 16));
        a0 += b2f((unsigned short)w2); a1 += b2f((unsigned short)(w2 >> 16));
        a0 += b2f((unsigned short)w3); a1 += b2f((unsigned short)(w3 >> 16));
        a0 += b2f((unsigned short)w4); a1 += b2f((unsigned short)(w4 >> 16));
        a0 += b2f((unsigned short)w5); a1 += b2f((unsigned short)(w5 >> 16));
        a0 += b2f((unsigned short)w6); a1 += b2f((unsigned short)(w6 >> 16));
        a0 += b2f((unsigned short)w7); a1 += b2f((unsigned short)(w7 >> 16));
    }
    for (; j < c; j++){
        size_t s = (size_t)csr[start + j];
        unsigned v = *(const unsigned*)(hs + s * 64 + hl * 2);
        a0 += b2f((unsigned short)v);
        a1 += b2f((unsigned short)(v >> 16));
    }
    float dv = dinv[node];
    float2 bb = ((const float2*)b)[hl];
    float r0 = fmaf(dv, a0, bb.x);
    float r1 = fmaf(dv, a1, bb.y);
    *(unsigned*)(z + i * 64 + hl * 2) = (unsigned)f2b(r0) | ((unsigned)f2b(r1) << 16);
}

// ------- decode: out[e] = dot(z2[s], z2[t]); 4 edges/wave, uint2 loads ---------
__global__ __launch_bounds__(256) void k_decode(const unsigned short* __restrict__ z,
                                                const int* __restrict__ es,
                                                const int* __restrict__ et,
                                                float* __restrict__ out, int m){
    int wv = (blockIdx.x * 256 + threadIdx.x) >> 6;
    int lane = threadIdx.x & 63;
    int e = wv * 4 + (lane >> 4);
    int ql = lane & 15;
    float p = 0.f;
    if (e < m){
        size_t s = (size_t)es[e], t2 = (size_t)et[e];
        uint2 vs = *(const uint2*)(z + s * 64 + ql * 4);
        uint2 vt = *(const uint2*)(z + t2 * 64 + ql * 4);
        p = b2f((unsigned short)vs.x) * b2f((unsigned short)vt.x)
          + b2f((unsigned short)(vs.x >> 16)) * b2f((unsigned short)(vt.x >> 16))
          + b2f((unsigned short)vs.y) * b2f((unsigned short)vt.y)
          + b2f((unsigned short)(vs.y >> 16)) * b2f((unsigned short)(vt.y >> 16));
    }
    #pragma unroll
    for (int o = 8; o > 0; o >>= 1) p += __shfl_xor(p, o);
    if (ql == 0 && e < m) out[e] = p;
}

// ---------------- launcher ----------------

extern "C" void kernel_launch(void* const* d_in, const int* in_sizes, int n_in,
                              void* d_out, int out_size, void* d_ws, size_t ws_size,
                              hipStream_t stream){
    const float* x   = (const float*)d_in[0];
    const int*   ei  = (const int*)d_in[1];
    const int*   eli = (const int*)d_in[2];
    const float* W1  = (const float*)d_in[3];
    const float* b1  = (const float*)d_in[4];
    const float* W2  = (const float*)d_in[5];
    const float* b2  = (const float*)d_in[6];
    float* out = (float*)d_out;

    int N_  = in_sizes[0] / 128;
    int E_  = in_sizes[1] / 2;
    int EL_ = in_sizes[2] / 2;
    int NBINS = (N_ + 127) >> 7;           // 782 for N=100k (must be <= 1024)
    const int EPB = 4096;
    int NBLK = (E_ + EPB - 1) / EPB;       // 391 for E=1.6M

    char* w = (char*)d_ws;
    size_t o = 0;
    auto alloc = [&](size_t bytes) -> size_t {
        size_t r = o; o += (bytes + 511) & ~(size_t)511; return r;
    };
    size_t o_cnt  = alloc((size_t)N_ * 4);
    size_t o_off  = alloc((size_t)N_ * 4);
    size_t o_dinv = alloc((size_t)N_ * 4);
    size_t o_gcur = alloc((size_t)NBINS * 4);
    size_t o_csr  = alloc((size_t)E_ * 4);
    size_t o_wf1  = alloc(16384 * 2);
    size_t o_w2p  = alloc(4096 * 4);
    size_t o_hs1  = alloc((size_t)N_ * 128 * 2);   // 25.6MB; also hosts slab & z2
    size_t o_hs2  = alloc((size_t)N_ * 64 * 2);

    int* cnt  = (int*)(w + o_cnt);
    int* off  = (int*)(w + o_off);
    float* dinv = (float*)(w + o_dinv);
    int* gcur = (int*)(w + o_gcur);
    int* csr  = (int*)(w + o_csr);
    unsigned short* wf1 = (unsigned short*)(w + o_wf1);
    unsigned* w2p = (unsigned*)(w + o_w2p);
    unsigned short* hs1 = (unsigned short*)(w + o_hs1);
    unsigned short* hs2 = (unsigned short*)(w + o_hs2);
    unsigned short* z2  = (unsigned short*)(w + o_hs1);  // hs1 dead after agg1g2

    // slab aliases the hs1 region (dead until k_gemm1 writes hs1):
    // NBINS*4096*4B = 12.8MB <= 25.6MB
    unsigned* slab = (unsigned*)(w + o_hs1);

    const int AGG1_BLOCKS = 2048;          // 8 blocks/CU (18KB LDS) -> 32 waves/CU
    int nwaves = AGG1_BLOCKS * 4;

    (void)hipMemsetAsync(gcur, 0, (size_t)NBINS * 4, stream);
    k_scatter2<<<NBLK, 256, 0, stream>>>(ei, ei + E_, gcur, slab, E_, NBINS);
    k_binsort <<<NBINS, 256, 0, stream>>>(slab, gcur, csr, cnt, off, dinv, N_, NBINS);
    k_wconv   <<<24, 256, 0, stream>>>(W1, W2, wf1, w2p);
    k_gemm1   <<<(N_ + 63) / 64, 256, 0, stream>>>(x, wf1, dinv, hs1, N_);
    k_agg1g2  <<<AGG1_BLOCKS, 256, 0, stream>>>(hs1, off, cnt, csr, dinv, b1, w2p, hs2, N_, nwaves);
    k_agg2    <<<(N_ + 7) / 8, 256, 0, stream>>>(hs2, off, cnt, csr, dinv, b2, z2, N_);
    k_decode  <<<(EL_ + 15) / 16, 256, 0, stream>>>(z2, eli, eli + EL_, out, EL_);
}

// Round 13
// 270.198 us; speedup vs baseline: 1.5125x; 1.0355x over previous
//
#include <hip/hip_runtime.h>
#include <stdint.h>

typedef __bf16 bf16x8 __attribute__((ext_vector_type(8)));
typedef float  floatx4 __attribute__((ext_vector_type(4)));
typedef float  floatx2 __attribute__((ext_vector_type(2)));
typedef __fp16 h2 __attribute__((ext_vector_type(2)));

__device__ __forceinline__ unsigned short f2b(float x){
    unsigned u = __float_as_uint(x);
    u = u + 0x7FFFu + ((u >> 16) & 1u);          // RNE
    return (unsigned short)(u >> 16);
}
__device__ __forceinline__ float b2f(unsigned short h){
    return __uint_as_float(((unsigned)h) << 16);
}
__device__ __forceinline__ unsigned char f2f8(float x){
    int p = __builtin_amdgcn_cvt_pk_fp8_f32(x, x, 0, false);
    return (unsigned char)(p & 0xff);
}

// ================= CSR build: reservation counting sort (single pass) =========
// bin = dst >> 7 (128 nodes/bin). Slab capacity 4096/bin (mean 2046, sigma~45).
__global__ __launch_bounds__(256) void k_scatter2(const int* __restrict__ src,
                                                  const int* __restrict__ dst,
                                                  int* __restrict__ gcur,
                                                  unsigned* __restrict__ slab,
                                                  int E_, int nbins){
    __shared__ int h[1024];
    __shared__ unsigned wbuf[4096];
    __shared__ unsigned short bbuf[4096];
    int t = threadIdx.x, blk = blockIdx.x;
    for (int i = t; i < nbins; i += 256) h[i] = 0;
    __syncthreads();
    int base = blk * 4096;
    int valid = E_ - base; if (valid > 4096) valid = 4096;
    #pragma unroll
    for (int j = 0; j < 4; j++){
        int li = (j * 256 + t) * 4;
        int e = base + li;
        if (e < E_){
            int4 d = *(const int4*)(dst + e);
            int4 s = *(const int4*)(src + e);
            wbuf[li + 0] = ((unsigned)(d.x & 127) << 25) | (unsigned)s.x;
            wbuf[li + 1] = ((unsigned)(d.y & 127) << 25) | (unsigned)s.y;
            wbuf[li + 2] = ((unsigned)(d.z & 127) << 25) | (unsigned)s.z;
            wbuf[li + 3] = ((unsigned)(d.w & 127) << 25) | (unsigned)s.w;
            bbuf[li + 0] = (unsigned short)(d.x >> 7);
            bbuf[li + 1] = (unsigned short)(d.y >> 7);
            bbuf[li + 2] = (unsigned short)(d.z >> 7);
            bbuf[li + 3] = (unsigned short)(d.w >> 7);
            atomicAdd(&h[d.x >> 7], 1);
            atomicAdd(&h[d.y >> 7], 1);
            atomicAdd(&h[d.z >> 7], 1);
            atomicAdd(&h[d.w >> 7], 1);
        }
    }
    __syncthreads();
    for (int i = t; i < nbins; i += 256){
        int hv = h[i];
        h[i] = hv ? atomicAdd(&gcur[i], hv) : 0;
    }
    __syncthreads();
    for (int i = t; i < valid; i += 256){
        int bin = bbuf[i];
        int p = atomicAdd(&h[bin], 1);
        slab[(size_t)bin * 4096 + p] = wbuf[i];
    }
}

// one block per bin: computes its own boff prefix from gcur; local
// count/scan/rank in LDS; coalesced csr write; emits cnt/off/dinv.
__global__ __launch_bounds__(256) void k_binsort(const unsigned* __restrict__ slab,
                                                 const int* __restrict__ gcur,
                                                 int* __restrict__ csr,
                                                 int* __restrict__ cnt,
                                                 int* __restrict__ off,
                                                 float* __restrict__ dinv,
                                                 int n, int nbins){
    int b = blockIdx.x, t = threadIdx.x;
    __shared__ int sv[1024], sp[256];
    #pragma unroll
    for (int k = 0; k < 4; k++){
        int i = t * 4 + k;
        sv[i] = (i < nbins) ? gcur[i] : 0;
    }
    __syncthreads();
    int a0 = sv[t * 4], a1 = sv[t * 4 + 1], a2 = sv[t * 4 + 2], a3 = sv[t * 4 + 3];
    sp[t] = a0 + a1 + a2 + a3;
    __syncthreads();
    for (int o = 1; o < 256; o <<= 1){
        int v = (t >= o) ? sp[t - o] : 0;
        __syncthreads();
        sp[t] += v;
        __syncthreads();
    }
    int basep = t ? sp[t - 1] : 0;
    sv[t * 4]     = basep;
    sv[t * 4 + 1] = basep + a0;
    sv[t * 4 + 2] = basep + a0 + a1;
    sv[t * 4 + 3] = basep + a0 + a1 + a2;
    __syncthreads();
    int s0 = sv[b];
    int len = gcur[b];
    if (len > 4096) len = 4096;
    const unsigned* seg = slab + (size_t)b * 4096;
    __shared__ int cl[128], sc[128], cur[128];
    __shared__ unsigned buf[4096], outb[4096];
    if (t < 128){ cl[t] = 0; cur[t] = 0; }
    __syncthreads();
    for (int i = t; i < len; i += 256) buf[i] = seg[i];
    __syncthreads();
    for (int i = t; i < len; i += 256) atomicAdd(&cl[buf[i] >> 25], 1);
    __syncthreads();
    if (t < 128) sc[t] = cl[t];
    __syncthreads();
    for (int o = 1; o < 128; o <<= 1){
        int v = 0;
        if (t < 128 && t >= o) v = sc[t - o];
        __syncthreads();
        if (t < 128) sc[t] += v;
        __syncthreads();
    }
    for (int i = t; i < len; i += 256){
        unsigned w = buf[i];
        int nd = (int)(w >> 25);
        int p = (sc[nd] - cl[nd]) + atomicAdd(&cur[nd], 1);
        outb[p] = w & 0x1FFFFFFu;
    }
    __syncthreads();
    for (int i = t; i < len; i += 256) csr[s0 + i] = (int)outb[i];
    if (t < 128){
        int node = b * 128 + t;
        if (node < n){
            cnt[node] = cl[t];
            off[node] = s0 + (sc[t] - cl[t]);
            dinv[node] = rsqrtf((float)cl[t] + 1.0f);
        }
    }
}

// -------- init: W1 -> MFMA B-frag order; W2 -> packed f16 pairs; zero gcur ----
__global__ __launch_bounds__(256) void k_init(const float* __restrict__ W1,
                                              const float* __restrict__ W2,
                                              unsigned short* __restrict__ wf1,
                                              unsigned* __restrict__ w2p,
                                              int* __restrict__ gcur, int nbins){
    int blk = blockIdx.x, t = threadIdx.x;
    if (blk == 24){
        for (int i = t; i < nbins; i += 256) gcur[i] = 0;
        return;
    }
    int f = blk * 256 + t;
    if (f < 2048){
        int lane = f & 63;
        int ctkc = f >> 6;
        int kc = ctkc & 3, ct = ctkc >> 2;
        int col = ct * 16 + (lane & 15);
        int k0  = kc * 32 + (lane >> 4) * 8;
        unsigned short* d = wf1 + (size_t)f * 8;
        #pragma unroll
        for (int j = 0; j < 8; j++) d[j] = f2b(W1[(k0 + j) * 128 + col]);
    } else if (f < 2048 + 4096){
        int lf = f - 2048;
        int kp = lf >> 6, lane = lf & 63;
        h2 p = __builtin_amdgcn_cvt_pkrtz(W2[(2 * kp) * 64 + lane],
                                          W2[(2 * kp + 1) * 64 + lane]);
        w2p[lf] = __builtin_bit_cast(unsigned, p);
    }
}

// ---------------- GEMM1: hs1 = fp8( (x @ W1) * dinv[row] ), row-major ---------
__global__ __launch_bounds__(256) void k_gemm1(const float* __restrict__ x,
                                               const unsigned short* __restrict__ wf,
                                               const float* __restrict__ dinv,
                                               unsigned char* __restrict__ hs, int n){
    __shared__ unsigned short Wl[16384];
    __shared__ unsigned short Al[64 * 136];
    int t = threadIdx.x;
    long rowBase = (long)blockIdx.x * 64;
    {
        const uint4* s4 = (const uint4*)wf;
        uint4* d4 = (uint4*)Wl;
        #pragma unroll
        for (int i = 0; i < 8; i++) d4[t + i * 256] = s4[t + i * 256];
    }
    {
        const float4* xs = (const float4*)(x + rowBase * 128);
        #pragma unroll
        for (int k = 0; k < 8; k++){
            int i = t + k * 256;
            int r = i >> 5, c4 = (i & 31) << 2;
            float4 v = make_float4(0.f, 0.f, 0.f, 0.f);
            if (rowBase + r < n) v = xs[i];
            unsigned lo = (unsigned)f2b(v.x) | ((unsigned)f2b(v.y) << 16);
            unsigned hi = (unsigned)f2b(v.z) | ((unsigned)f2b(v.w) << 16);
            *(uint2*)&Al[r * 136 + c4] = make_uint2(lo, hi);
        }
    }
    __syncthreads();
    int w = t >> 6, lane = t & 63, lr = lane & 15, q = lane >> 4;
    floatx4 zero = {0.f, 0.f, 0.f, 0.f};
    floatx4 acc[8];
    #pragma unroll
    for (int ct = 0; ct < 8; ct++) acc[ct] = zero;
    #pragma unroll
    for (int kc = 0; kc < 4; kc++){
        bf16x8 af = *(const bf16x8*)&Al[(w * 16 + lr) * 136 + kc * 32 + q * 8];
        #pragma unroll
        for (int ct = 0; ct < 8; ct++){
            bf16x8 bf = *(const bf16x8*)&Wl[((ct * 4 + kc) * 64 + lane) * 8];
            acc[ct] = __builtin_amdgcn_mfma_f32_16x16x32_bf16(af, bf, acc[ct], 0, 0, 0);
        }
    }
    long r0 = rowBase + w * 16 + q * 4;
    #pragma unroll
    for (int r = 0; r < 4; r++){
        long row = r0 + r;
        if (row >= n) continue;
        float dv = dinv[row];
        unsigned char* orow = hs + row * 128 + lr;
        #pragma unroll
        for (int ct = 0; ct < 8; ct++) orow[ct * 16] = f2f8(acc[ct][r] * dv);
    }
}

// ---- fused agg1 + gemm2: hs2[i] = bf16( (relu(dinv_i*(sum hs1[src]+hs1[i])+b1) @ W2) * dinv_i )
// hs1 is fp8 e4m3 (12.8MB table, rows 128B): halves the random-row fill traffic.
__global__ __launch_bounds__(256) void k_agg1g2(const unsigned char* __restrict__ hs,
                                                const int* __restrict__ off,
                                                const int* __restrict__ cnt,
                                                const int* __restrict__ csr,
                                                const float* __restrict__ dinv,
                                                const float* __restrict__ b1,
                                                const unsigned* __restrict__ w2p,
                                                unsigned short* __restrict__ hs2,
                                                int n, int nwaves){
    __shared__ unsigned W2l[4096];     // 16 KB packed half2 [kp][lane]
    __shared__ unsigned zp[4][64];     // packed half2 z row per wave
    int t = threadIdx.x;
    {
        const uint4* w4 = (const uint4*)w2p;
        uint4* d4 = (uint4*)W2l;
        #pragma unroll
        for (int i = 0; i < 4; i++) d4[t + i * 256] = w4[t + i * 256];
    }
    __syncthreads();
    int wband = t >> 6, lane = t & 63;
    float2 bb = ((const float2*)b1)[lane];
    for (int wid = blockIdx.x * 4 + wband; wid < n; wid += nwaves){
        size_t i = (size_t)wid;
        int start = off[wid], c = cnt[wid];
        unsigned short v0 = *(const unsigned short*)(hs + i * 128 + lane * 2);
        floatx2 f0 = __builtin_amdgcn_cvt_pk_f32_fp8((int)v0, false);
        float a0 = f0.x, a1 = f0.y;
        int j = 0;
        for (; j + 8 <= c; j += 8){
            size_t s0 = (size_t)csr[start + j + 0];
            size_t s1 = (size_t)csr[start + j + 1];
            size_t s2 = (size_t)csr[start + j + 2];
            size_t s3 = (size_t)csr[start + j + 3];
            size_t s4 = (size_t)csr[start + j + 4];
            size_t s5 = (size_t)csr[start + j + 5];
            size_t s6 = (size_t)csr[start + j + 6];
            size_t s7 = (size_t)csr[start + j + 7];
            unsigned short w0 = *(const unsigned short*)(hs + s0 * 128 + lane * 2);
            unsigned short w1 = *(const unsigned short*)(hs + s1 * 128 + lane * 2);
            unsigned short w2 = *(const unsigned short*)(hs + s2 * 128 + lane * 2);
            unsigned short w3 = *(const unsigned short*)(hs + s3 * 128 + lane * 2);
            unsigned short w4 = *(const unsigned short*)(hs + s4 * 128 + lane * 2);
            unsigned short w5 = *(const unsigned short*)(hs + s5 * 128 + lane * 2);
            unsigned short w6 = *(const unsigned short*)(hs + s6 * 128 + lane * 2);
            unsigned short w7 = *(const unsigned short*)(hs + s7 * 128 + lane * 2);
            floatx2 g0 = __builtin_amdgcn_cvt_pk_f32_fp8((int)w0, false);
            floatx2 g1 = __builtin_amdgcn_cvt_pk_f32_fp8((int)w1, false);
            floatx2 g2 = __builtin_amdgcn_cvt_pk_f32_fp8((int)w2, false);
            floatx2 g3 = __builtin_amdgcn_cvt_pk_f32_fp8((int)w3, false);
            floatx2 g4 = __builtin_amdgcn_cvt_pk_f32_fp8((int)w4, false);
            floatx2 g5 = __builtin_amdgcn_cvt_pk_f32_fp8((int)w5, false);
            floatx2 g6 = __builtin_amdgcn_cvt_pk_f32_fp8((int)w6, false);
            floatx2 g7 = __builtin_amdgcn_cvt_pk_f32_fp8((int)w7, false);
            a0 += g0.x; a1 += g0.y;
            a0 += g1.x; a1 += g1.y;
            a0 += g2.x; a1 += g2.y;
            a0 += g3.x; a1 += g3.y;
            a0 += g4.x; a1 += g4.y;
            a0 += g5.x; a1 += g5.y;
            a0 += g6.x; a1 += g6.y;
            a0 += g7.x; a1 += g7.y;
        }
        for (; j < c; j++){
            size_t s = (size_t)csr[start + j];
            unsigned short v = *(const unsigned short*)(hs + s * 128 + lane * 2);
            floatx2 g = __builtin_amdgcn_cvt_pk_f32_fp8((int)v, false);
            a0 += g.x; a1 += g.y;
        }
        float dv = dinv[wid];
        float z0 = fmaxf(fmaf(dv, a0, bb.x), 0.f);
        float z1 = fmaxf(fmaf(dv, a1, bb.y), 0.f);
        // wave-synchronous LDS round trip (per-wave buffer, no barrier)
        zp[wband][lane] = __builtin_bit_cast(unsigned, __builtin_amdgcn_cvt_pkrtz(z0, z1));
        float acc0 = 0.f, acc1 = 0.f;
        #pragma unroll 8
        for (int kp = 0; kp < 64; kp += 2){
            h2 wa = __builtin_bit_cast(h2, W2l[kp * 64 + lane]);
            h2 wb = __builtin_bit_cast(h2, W2l[(kp + 1) * 64 + lane]);
            h2 za = __builtin_bit_cast(h2, zp[wband][kp]);
            h2 zb = __builtin_bit_cast(h2, zp[wband][kp + 1]);
            acc0 = __builtin_amdgcn_fdot2(za, wa, acc0, false);
            acc1 = __builtin_amdgcn_fdot2(zb, wb, acc1, false);
        }
        hs2[i * 64 + lane] = f2b((acc0 + acc1) * dv);
    }
}

// -------- aggregation layer 2: 2 nodes/wave (half-wave each), dword loads ------
__global__ __launch_bounds__(256) void k_agg2(const unsigned short* __restrict__ hs,
                                              const int* __restrict__ off,
                                              const int* __restrict__ cnt,
                                              const int* __restrict__ csr,
                                              const float* __restrict__ dinv,
                                              const float* __restrict__ b,
                                              unsigned short* __restrict__ z, int n){
    int wv = (blockIdx.x * 256 + threadIdx.x) >> 6;
    int lane = threadIdx.x & 63;
    int half = lane >> 5, hl = lane & 31;
    int node = wv * 2 + half;
    if (node >= n) return;
    size_t i = (size_t)node;
    int start = off[node], c = cnt[node];
    unsigned v0 = *(const unsigned*)(hs + i * 64 + hl * 2);
    float a0 = b2f((unsigned short)v0);
    float a1 = b2f((unsigned short)(v0 >> 16));
    int j = 0;
    for (; j + 8 <= c; j += 8){
        size_t s0 = (size_t)csr[start + j + 0];
        size_t s1 = (size_t)csr[start + j + 1];
        size_t s2 = (size_t)csr[start + j + 2];
        size_t s3 = (size_t)csr[start + j + 3];
        size_t s4 = (size_t)csr[start + j + 4];
        size_t s5 = (size_t)csr[start + j + 5];
        size_t s6 = (size_t)csr[start + j + 6];
        size_t s7 = (size_t)csr[start + j + 7];
        unsigned w0 = *(const unsigned*)(hs + s0 * 64 + hl * 2);
        unsigned w1 = *(const unsigned*)(hs + s1 * 64 + hl * 2);
        unsigned w2 = *(const unsigned*)(hs + s2 * 64 + hl * 2);
        unsigned w3 = *(const unsigned*)(hs + s3 * 64 + hl * 2);
        unsigned w4 = *(const unsigned*)(hs + s4 * 64 + hl * 2);
        unsigned w5 = *(const unsigned*)(hs + s5 * 64 + hl * 2);
        unsigned w6 = *(const unsigned*)(hs + s6 * 64 + hl * 2);
        unsigned w7 = *(const unsigned*)(hs + s7 * 64 + hl * 2);
        a0 += b2f((unsigned short)w0); a1 += b2f((unsigned short)(w0 >> 16));
        a0 += b2f((unsigned short)w1); a1 += b2f((unsigned short)(w1 >> 16));
        a0 += b2f((unsigned short)w2); a1 += b2f((unsigned short)(w2 >> 16));
        a0 += b2f((unsigned short)w3); a1 += b2f((unsigned short)(w3 >> 16));
        a0 += b2f((unsigned short)w4); a1 += b2f((unsigned short)(w4 >> 16));
        a0 += b2f((unsigned short)w5); a1 += b2f((unsigned short)(w5 >> 16));
        a0 += b2f((unsigned short)w6); a1 += b2f((unsigned short)(w6 >> 16));
        a0 += b2f((unsigned short)w7); a1 += b2f((unsigned short)(w7 >> 16));
    }
    for (; j < c; j++){
        size_t s = (size_t)csr[start + j];
        unsigned v = *(const unsigned*)(hs + s * 64 + hl * 2);
        a0 += b2f((unsigned short)v);
        a1 += b2f((unsigned short)(v >> 16));
    }
    float dv = dinv[node];
    float2 bb = ((const float2*)b)[hl];
    float r0 = fmaf(dv, a0, bb.x);
    float r1 = fmaf(dv, a1, bb.y);
    *(unsigned*)(z + i * 64 + hl * 2) = (unsigned)f2b(r0) | ((unsigned)f2b(r1) << 16);
}

// ------- decode: out[e] = dot(z2[s], z2[t]); 4 edges/wave, uint2 loads ---------
__global__ __launch_bounds__(256) void k_decode(const unsigned short* __restrict__ z,
                                                const int* __restrict__ es,
                                                const int* __restrict__ et,
                                                float* __restrict__ out, int m){
    int wv = (blockIdx.x * 256 + threadIdx.x) >> 6;
    int lane = threadIdx.x & 63;
    int e = wv * 4 + (lane >> 4);
    int ql = lane & 15;
    float p = 0.f;
    if (e < m){
        size_t s = (size_t)es[e], t2 = (size_t)et[e];
        uint2 vs = *(const uint2*)(z + s * 64 + ql * 4);
        uint2 vt = *(const uint2*)(z + t2 * 64 + ql * 4);
        p = b2f((unsigned short)vs.x) * b2f((unsigned short)vt.x)
          + b2f((unsigned short)(vs.x >> 16)) * b2f((unsigned short)(vt.x >> 16))
          + b2f((unsigned short)vs.y) * b2f((unsigned short)vt.y)
          + b2f((unsigned short)(vs.y >> 16)) * b2f((unsigned short)(vt.y >> 16));
    }
    #pragma unroll
    for (int o = 8; o > 0; o >>= 1) p += __shfl_xor(p, o);
    if (ql == 0 && e < m) out[e] = p;
}

// ---------------- launcher ----------------

extern "C" void kernel_launch(void* const* d_in, const int* in_sizes, int n_in,
                              void* d_out, int out_size, void* d_ws, size_t ws_size,
                              hipStream_t stream){
    const float* x   = (const float*)d_in[0];
    const int*   ei  = (const int*)d_in[1];
    const int*   eli = (const int*)d_in[2];
    const float* W1  = (const float*)d_in[3];
    const float* b1  = (const float*)d_in[4];
    const float* W2  = (const float*)d_in[5];
    const float* b2  = (const float*)d_in[6];
    float* out = (float*)d_out;

    int N_  = in_sizes[0] / 128;
    int E_  = in_sizes[1] / 2;
    int EL_ = in_sizes[2] / 2;
    int NBINS = (N_ + 127) >> 7;           // 782 for N=100k (must be <= 1024)
    const int EPB = 4096;
    int NBLK = (E_ + EPB - 1) / EPB;       // 391 for E=1.6M

    char* w = (char*)d_ws;
    size_t o = 0;
    auto alloc = [&](size_t bytes) -> size_t {
        size_t r = o; o += (bytes + 511) & ~(size_t)511; return r;
    };
    size_t o_cnt  = alloc((size_t)N_ * 4);
    size_t o_off  = alloc((size_t)N_ * 4);
    size_t o_dinv = alloc((size_t)N_ * 4);
    size_t o_gcur = alloc((size_t)NBINS * 4);
    size_t o_csr  = alloc((size_t)E_ * 4);
    size_t o_wf1  = alloc(16384 * 2);
    size_t o_w2p  = alloc(4096 * 4);
    size_t o_slab = alloc((size_t)NBINS * 4096 * 4);   // 12.8MB; also z2 after binsort+agg2
    size_t o_hs1  = alloc((size_t)N_ * 128);           // fp8 table, 12.8MB
    size_t o_hs2  = alloc((size_t)N_ * 64 * 2);        // bf16 table, 12.8MB

    int* cnt  = (int*)(w + o_cnt);
    int* off  = (int*)(w + o_off);
    float* dinv = (float*)(w + o_dinv);
    int* gcur = (int*)(w + o_gcur);
    int* csr  = (int*)(w + o_csr);
    unsigned short* wf1 = (unsigned short*)(w + o_wf1);
    unsigned* w2p = (unsigned*)(w + o_w2p);
    unsigned* slab = (unsigned*)(w + o_slab);
    unsigned char* hs1 = (unsigned char*)(w + o_hs1);
    unsigned short* hs2 = (unsigned short*)(w + o_hs2);
    unsigned short* z2  = (unsigned short*)(w + o_slab);  // slab dead after binsort

    const int AGG1_BLOCKS = 2048;          // 8 blocks/CU (18KB LDS) -> 32 waves/CU
    int nwaves = AGG1_BLOCKS * 4;

    k_init    <<<25, 256, 0, stream>>>(W1, W2, wf1, w2p, gcur, NBINS);
    k_scatter2<<<NBLK, 256, 0, stream>>>(ei, ei + E_, gcur, slab, E_, NBINS);
    k_binsort <<<NBINS, 256, 0, stream>>>(slab, gcur, csr, cnt, off, dinv, N_, NBINS);
    k_gemm1   <<<(N_ + 63) / 64, 256, 0, stream>>>(x, wf1, dinv, hs1, N_);
    k_agg1g2  <<<AGG1_BLOCKS, 256, 0, stream>>>(hs1, off, cnt, csr, dinv, b1, w2p, hs2, N_, nwaves);
    k_agg2    <<<(N_ + 7) / 8, 256, 0, stream>>>(hs2, off, cnt, csr, dinv, b2, z2, N_);
    k_decode  <<<(EL_ + 15) / 16, 256, 0, stream>>>(z2, eli, eli + EL_, out, EL_);
}